// Round 8
// baseline (214.455 us; speedup 1.0000x reference)
//
#include <hip/hip_runtime.h>
#include <stdint.h>

// z (32,384,28,28) fp32; codebook (2048,384) fp32.
// N tokens = 25088, D = 384, K = 2048. out = z_q (9633792 f32) + loss (1 f32).
#define M_TOK 25088
#define D_DIM 384
#define K_CB  2048
#define OUT_ELEMS 9633792

typedef __attribute__((ext_vector_type(8))) short short8;
typedef __attribute__((ext_vector_type(4))) float f32x4;

static __device__ __forceinline__ unsigned short f2bf(float f) {
    uint32_t u = __float_as_uint(f);
    u += 0x7FFF + ((u >> 16) & 1);   // RNE
    return (unsigned short)(u >> 16);
}
static __device__ __forceinline__ float bf2f(unsigned short h) {
    return __uint_as_float(((uint32_t)h) << 16);
}
static __device__ __forceinline__ void gl_lds16(const void* g, void* l) {
    __builtin_amdgcn_global_load_lds((const __attribute__((address_space(1))) void*)g,
                                     (__attribute__((address_space(3))) void*)l,
                                     16, 0, 0);
}

// ---------------- fused: z transpose (+ ||z||^2 partials) and codebook prep ----------------
__global__ __launch_bounds__(256) void prep_transpose_kernel(
    const float* __restrict__ z, const float* __restrict__ cb,
    unsigned short* __restrict__ zf, float* __restrict__ znp,
    unsigned short* __restrict__ cb16, float* __restrict__ cnorm) {
    __shared__ unsigned short tile[64 * 64];
    __shared__ float zred[4][64];
    int bid = blockIdx.x;
    int t = threadIdx.x;
    if (bid >= 2496) {               // codebook prep: 512 blocks x 4 rows
        int lane = t & 63, wv = t >> 6;
        int row = (bid - 2496) * 4 + wv;
        const float* src = cb + (size_t)row * D_DIM;
        unsigned short* dst = cb16 + (size_t)row * D_DIM;
        float ss = 0.f;
#pragma unroll
        for (int i = 0; i < 6; ++i) {
            float v = src[lane + i * 64];
            dst[lane + i * 64] = f2bf(v);
            ss += v * v;
        }
#pragma unroll
        for (int d = 32; d; d >>= 1) ss += __shfl_xor(ss, d);
        if (lane == 0) cnorm[row] = ss;
        return;
    }
    // transpose path: (b,c,s) fp32 -> (token,c) bf16, 64x64 LDS tiles, XOR swizzle
    int sT = bid % 13;
    int rem = bid / 13;
    int cT = rem % 6;
    int b  = rem / 6;
    int c0 = cT * 64, s0 = sT * 64;
    int ls = t & 63;
    int wv = t >> 6;
    float ss = 0.f;
#pragma unroll
    for (int p = 0; p < 16; ++p) {
        int ci = p * 4 + wv;
        int s = s0 + ls;
        float v = 0.f;
        if (s < 784) v = z[(size_t)(b * 384 + c0 + ci) * 784 + s];
        ss += v * v;
        int cx = ci ^ ((ls & 7) << 3);
        tile[ls * 64 + cx] = f2bf(v);
    }
    zred[wv][ls] = ss;
    __syncthreads();
    if (t < 64) {
        int s = s0 + t;
        if (s < 784)
            znp[cT * M_TOK + b * 784 + s] =
                (zred[0][t] + zred[1][t]) + (zred[2][t] + zred[3][t]);
    }
    int si = t >> 2, sub = t & 3;
    int s = s0 + si;
    if (s >= 784) return;
    int x = si & 7;
    int base0 = ((sub ^ (x >> 1)) << 4) | ((x & 1) << 3);
    int base1 = base0 ^ 8;
    uint4 v0 = *(const uint4*)&tile[si * 64 + base0];
    uint4 v1 = *(const uint4*)&tile[si * 64 + base1];
    size_t ro = (size_t)(b * 784 + s) * 384 + c0 + sub * 16;
    *(uint4*)(zf + ro)     = v0;
    *(uint4*)(zf + ro + 8) = v1;
}

// ---------------- distance GEMM + FULL argmin: A-resident, B -> registers ----------------
// grid 256 (1 block/CU, 98 tokens padded to 112 rows). 8 waves free-run — NO
// barriers in the main loop. A k-major in LDS [12 kc][112 row][64 B] (86 KB,
// staged once). B streams straight into registers: lane (r,q) loads its own
// MFMA fragment cb16[col0+r][ks*32+q*8] as one dwordx4; 3-buffer pipeline
// (b0/b1/b2), prefetch distance 3, compiler-counted vmcnt. 48 steps = 4 mc x
// 12 ks; per step 7 ds_read_b128 + 4 glb loads + 28 MFMA. Waves on a SIMD run
// at independent phases -> mutual latency hiding (no convoy).

#define STEP(KS, BUF, NXB, NXKS) do { \
    const char* Ap_ = Ar + (KS) * 7168; \
    _Pragma("unroll") for (int mt = 0; mt < 7; ++mt) { \
        short8 av = *(const short8*)(Ap_ + mt * 1024); \
        acc[mt][0] = __builtin_amdgcn_mfma_f32_16x16x32_bf16(av, BUF[0], acc[mt][0], 0, 0, 0); \
        acc[mt][1] = __builtin_amdgcn_mfma_f32_16x16x32_bf16(av, BUF[1], acc[mt][1], 0, 0, 0); \
        acc[mt][2] = __builtin_amdgcn_mfma_f32_16x16x32_bf16(av, BUF[2], acc[mt][2], 0, 0, 0); \
        acc[mt][3] = __builtin_amdgcn_mfma_f32_16x16x32_bf16(av, BUF[3], acc[mt][3], 0, 0, 0); \
    } \
    BUF[0] = *(const short8*)((NXB) + (NXKS) * 64); \
    BUF[1] = *(const short8*)((NXB) + 12288 + (NXKS) * 64); \
    BUF[2] = *(const short8*)((NXB) + 24576 + (NXKS) * 64); \
    BUF[3] = *(const short8*)((NXB) + 36864 + (NXKS) * 64); \
} while (0)

__global__ __launch_bounds__(512, 2) void argmin8_kernel(
    const unsigned short* __restrict__ zf, const unsigned short* __restrict__ cb16,
    const float* __restrict__ cnorm, int* __restrict__ midx, float* __restrict__ mdist) {
    extern __shared__ char As[];     // 90,112 B ([12 kc][112 row][64 B] uses 86,016)

    int t = threadIdx.x;
    int lane = t & 63, wave = t >> 6;
    int r = lane & 15, q = lane >> 4;
    int blk = blockIdx.x;            // 256 blocks x 98 tokens

    const char* abase = (const char*)zf + (size_t)blk * 75264;   // 98*768

    // ---- A prologue: [row][k] global -> [kc][row][64B] LDS, swizzled src ----
#pragma unroll
    for (int it = 0; it < 11; ++it) {
        uint32_t o   = it * 8192u + (uint32_t)t * 16u;
        uint32_t kc  = o / 7168u;
        uint32_t rem = o - kc * 7168u;
        uint32_t row = rem >> 6;
        uint32_t byt = rem & 63u;
        gl_lds16(abase + row * 768u + kc * 64u + (byt ^ ((row & 3u) << 4)), As + o);
    }
    __builtin_amdgcn_sched_barrier(0);

    // ---- B prologue: ks 0,1,2 of mc 0 into b0,b1,b2 ----
    const char* bptr = (const char*)cb16 + (uint32_t)(wave * 64 + r) * 768u + (uint32_t)q * 16u;
    short8 b0[4], b1[4], b2[4];
#pragma unroll
    for (int nt = 0; nt < 4; ++nt) {
        b0[nt] = *(const short8*)(bptr + nt * 12288);
        b1[nt] = *(const short8*)(bptr + nt * 12288 + 64);
        b2[nt] = *(const short8*)(bptr + nt * 12288 + 128);
    }
    asm volatile("s_waitcnt vmcnt(0)" ::: "memory");
    __builtin_amdgcn_s_barrier();
    __builtin_amdgcn_sched_barrier(0);

    // fragment read geometry (loop-invariant)
    const char* Ar = As + (uint32_t)r * 64u + (((uint32_t)q * 16u) ^ (((uint32_t)r & 3u) << 4));

    uint32_t pmin[28];
#pragma unroll
    for (int i = 0; i < 28; ++i) pmin[i] = 0xFFFFFFFFu;
    f32x4 acc[7][4];
    const f32x4 zero4 = {0.f, 0.f, 0.f, 0.f};

    int ncolb = 0;
    const char* bmc = bptr;
#pragma unroll 1
    for (int mc = 0; mc < 4; ++mc) {
        const char* bnx = (mc < 3) ? (bmc + 393216) : bmc;   // mc=3: harmless reload
        float cn_[4];
#pragma unroll
        for (int nt = 0; nt < 4; ++nt)
            cn_[nt] = cnorm[ncolb + wave * 64 + nt * 16 + r];
#pragma unroll
        for (int mt = 0; mt < 7; ++mt)
#pragma unroll
            for (int nt = 0; nt < 4; ++nt) acc[mt][nt] = zero4;

        STEP(0, b0, bmc, 3);  STEP(1, b1, bmc, 4);  STEP(2, b2, bmc, 5);
        STEP(3, b0, bmc, 6);  STEP(4, b1, bmc, 7);  STEP(5, b2, bmc, 8);
        STEP(6, b0, bmc, 9);  STEP(7, b1, bmc, 10); STEP(8, b2, bmc, 11);
        STEP(9, b0, bnx, 0);  STEP(10, b1, bnx, 1); STEP(11, b2, bnx, 2);

        // score + packed running argmin: u = (bits(1+score) & ~0x7FF) | col
#pragma unroll
        for (int nt = 0; nt < 4; ++nt) {
            uint32_t colp = (uint32_t)(ncolb + wave * 64 + nt * 16 + r);
            float cn1 = 1.0f + cn_[nt];
#pragma unroll
            for (int mt = 0; mt < 7; ++mt)
#pragma unroll
                for (int j = 0; j < 4; ++j) {
                    float s1 = fmaf(acc[mt][nt][j], -2.0f, cn1);
                    uint32_t u = (__float_as_uint(s1) & 0xFFFFF800u) | colp;
                    int sl = mt * 4 + j;
                    pmin[sl] = u < pmin[sl] ? u : pmin[sl];
                }
        }
        bmc = bnx;
        ncolb += 512;
    }

    // ---- final reduce: 16-lane shfl per row-slot, cross-wave via LDS ----
    __syncthreads();
    uint32_t* comb = (uint32_t*)As;      // [8 wave][112 row], A region reused
#pragma unroll
    for (int sl = 0; sl < 28; ++sl) {
        uint32_t v = pmin[sl];
#pragma unroll
        for (int d = 1; d < 16; d <<= 1) {
            uint32_t ov = __shfl_xor(v, d);
            v = ov < v ? ov : v;
        }
        if (r == 0) {
            int row = (sl >> 2) * 16 + q * 4 + (sl & 3);
            comb[wave * 112 + row] = v;
        }
    }
    __syncthreads();
    if (t < 98) {
        uint32_t m = comb[t];
#pragma unroll
        for (int w = 1; w < 8; ++w) {
            uint32_t mw = comb[w * 112 + t];
            m = mw < m ? mw : m;
        }
        int n = blk * 98 + t;
        midx[n]  = (int)(m & 0x7FFu);
        mdist[n] = __uint_as_float(m & 0xFFFFF800u) - 1.0f;
    }
}

// ---------------- gather + output + loss ----------------
__global__ __launch_bounds__(256) void gather_combine_kernel(
    const float* __restrict__ cb, const int* __restrict__ midx,
    const float* __restrict__ mdist, const float* __restrict__ znp,
    float* __restrict__ out) {
    __shared__ unsigned short tile[56 * 392];
    __shared__ int lidx[56];
    int t = threadIdx.x;
    int bid = blockIdx.x;                 // 448 = 32 b * 14 sT
    int b = bid / 14, sT = bid % 14;
    int n0 = b * 784 + sT * 56;
    float lt = 0.f;
    if (t < 56) {
        int n = n0 + t;
        lidx[t] = midx[n];
        float zn = 0.f;
#pragma unroll
        for (int cT = 0; cT < 6; ++cT) zn += znp[cT * M_TOK + n];
        lt = mdist[n] + zn;               // ~ ||z_n - c_idx||^2
    }
    if (t < 64) {
#pragma unroll
        for (int d = 32; d; d >>= 1) lt += __shfl_xor(lt, d);
        if (t == 0) atomicAdd(out + OUT_ELEMS, lt * (1.25f / (float)OUT_ELEMS));
    }
    __syncthreads();
#pragma unroll
    for (int p = 0; p < 21; ++p) {
        int e = (p * 256 + t) * 4;
        int tok = e / 384;
        int c = e - tok * 384;
        int idx = lidx[tok];
        float4 v = *(const float4*)(cb + (size_t)idx * 384 + c);
        uint2 u;
        u.x = (uint32_t)f2bf(v.x) | ((uint32_t)f2bf(v.y) << 16);
        u.y = (uint32_t)f2bf(v.z) | ((uint32_t)f2bf(v.w) << 16);
        *(uint2*)&tile[tok * 392 + c] = u;
    }
    __syncthreads();
#pragma unroll
    for (int p = 0; p < 42; ++p) {
        int pp = p * 256 + t;
        int c = pp / 28;
        int j = (pp - c * 28) * 2;
        float f0 = bf2f(tile[j * 392 + c]);
        float f1 = bf2f(tile[(j + 1) * 392 + c]);
        size_t off = ((size_t)b * 384 + c) * 784 + (size_t)sT * 56 + j;
        float2 o; o.x = f0; o.y = f1;
        *(float2*)(out + off) = o;
    }
}

extern "C" void kernel_launch(void* const* d_in, const int* in_sizes, int n_in,
                              void* d_out, int out_size, void* d_ws, size_t ws_size,
                              hipStream_t stream) {
    const float* z  = (const float*)d_in[0];
    const float* cb = (const float*)d_in[1];
    float* out = (float*)d_out;
    char* ws = (char*)d_ws;

    // zf (token-major bf16 z, 19.3 MB) borrows d_out: fully consumed by
    // argmin8_kernel (prologue A-stage) before gather_combine overwrites d_out.
    unsigned short* zf = (unsigned short*)d_out;

    unsigned short* cb16 = (unsigned short*)ws;            // 1,572,864 B
    float*  cnorm   = (float*)(ws + 1572864);              //     8,192 B
    float*  znp     = (float*)(ws + 1581056);              //   602,112 B
    int*    midx    = (int*)(ws + 2183168);                //   100,352 B
    float*  mdist   = (float*)(ws + 2283520);              //   100,352 B

    hipMemsetAsync((void*)(out + OUT_ELEMS), 0, 4, stream);
    hipFuncSetAttribute((const void*)argmin8_kernel,
                        hipFuncAttributeMaxDynamicSharedMemorySize, 90112);
    prep_transpose_kernel<<<3008, 256, 0, stream>>>(z, cb, zf, znp, cb16, cnorm);
    argmin8_kernel<<<256, 512, 90112, stream>>>(zf, cb16, cnorm, midx, mdist);
    gather_combine_kernel<<<448, 256, 0, stream>>>(cb, midx, mdist, znp, out);
}